// Round 9
// baseline (434.565 us; speedup 1.0000x reference)
//
#include <hip/hip_runtime.h>
#include <math.h>

// Round 9: barrier-free flash. Fixed-scale softmax (R8) makes waves purely
// additive -> no shared state: K/V B-fragments read DIRECTLY from global
// (L1/L2-resident), only the wave-private Ps round-trip stays in LDS (9 KB).
// Zero __syncthreads in flash. LPT dispatch (qi = 63-qb). GEMMs unchanged.

typedef __bf16 bf16;
typedef __bf16 bf16x8 __attribute__((ext_vector_type(8)));
typedef float  f32x4  __attribute__((ext_vector_type(4)));

#define MFMA_BF16(a, b, c) __builtin_amdgcn_mfma_f32_16x16x32_bf16((a), (b), (c), 0, 0, 0)

#define SEQ  4096
#define NH   12
#define HD   64
#define DM   768
#define NQKV 2304
#define NPART 2
#define ATTN_SCALE 0.12f
#define RMS_EPS 1.1920928955078125e-07f

// ---------------------------------------------------------------------------
__global__ __launch_bounds__(256) void convert_in(const float* __restrict__ src,
                                                  bf16* __restrict__ dst, int n)
{
  const int i0 = (blockIdx.x * 256 + threadIdx.x) * 8;
  if (i0 >= n) return;
  f32x4 a = *(const f32x4*)(src + i0);
  f32x4 b = *(const f32x4*)(src + i0 + 4);
  bf16x8 o;
#pragma unroll
  for (int j = 0; j < 4; j++) { o[j] = (bf16)a[j]; o[j + 4] = (bf16)b[j]; }
  *(bf16x8*)(dst + i0) = o;
}

// ---------------------------------------------------------------------------
// 128x128-tile GEMM core (BK=32, 4 waves in 2x2 quadrants of 64x64).
// ---------------------------------------------------------------------------
__device__ __forceinline__ void gemm128_core(
    const bf16* __restrict__ A, const bf16* __restrict__ B,
    int m0, int n0, bf16 (*As)[40], bf16 (*Bs)[40], f32x4 acc[4][4])
{
  const int tid = threadIdx.x;
  const int lane = tid & 63, w = tid >> 6;
  const int c16 = lane & 15, q4 = lane >> 4;
  const int mo = (w & 1) * 64, no = (w >> 1) * 64;
  const int srow = tid >> 2, scol = (tid & 3) * 8;
  const f32x4 vzero = {0.f, 0.f, 0.f, 0.f};
#pragma unroll
  for (int i = 0; i < 4; i++)
#pragma unroll
    for (int j = 0; j < 4; j++) acc[i][j] = vzero;

  for (int k0 = 0; k0 < DM; k0 += 32) {
#pragma unroll
    for (int ps = 0; ps < 2; ps++) {
      const int r = srow + ps * 64;
      *(bf16x8*)&As[r][scol] = *(const bf16x8*)&A[(m0 + r) * DM + k0 + scol];
      *(bf16x8*)&Bs[r][scol] = *(const bf16x8*)&B[(n0 + r) * DM + k0 + scol];
    }
    __syncthreads();
    bf16x8 ar[4], br[4];
#pragma unroll
    for (int mq = 0; mq < 4; mq++)
      ar[mq] = *(const bf16x8*)&As[mo + mq * 16 + c16][q4 * 8];
#pragma unroll
    for (int nq = 0; nq < 4; nq++)
      br[nq] = *(const bf16x8*)&Bs[no + nq * 16 + c16][q4 * 8];
#pragma unroll
    for (int mq = 0; mq < 4; mq++)
#pragma unroll
      for (int nq = 0; nq < 4; nq++)
        acc[mq][nq] = MFMA_BF16(ar[mq], br[nq], acc[mq][nq]);
    __syncthreads();
  }
}

__global__ __launch_bounds__(256) void gemm_qkv(
    const bf16* __restrict__ A, const bf16* __restrict__ B,
    bf16* __restrict__ Qb, bf16* __restrict__ Kb, bf16* __restrict__ Vt)
{
  __shared__ bf16 As[128][40];
  __shared__ bf16 Bs[128][40];
  const int m0 = blockIdx.x * 128, n0 = blockIdx.y * 128;
  f32x4 acc[4][4];
  gemm128_core(A, B, m0, n0, As, Bs, acc);

  const int lane = threadIdx.x & 63, w = threadIdx.x >> 6;
  const int c16 = lane & 15, q4 = lane >> 4;
  const int mo = (w & 1) * 64, no = (w >> 1) * 64;
  const int kidx = blockIdx.y / 6;
  const int rbase = n0 - kidx * DM;
#pragma unroll
  for (int nq = 0; nq < 4; nq++) {
    const int rr = rbase + no + nq * 16 + c16;
    const int h = rr >> 6, d = rr & 63;
#pragma unroll
    for (int mq = 0; mq < 4; mq++) {
      const int mb = m0 + mo + mq * 16 + q4 * 4;
      if (kidx == 2) {
#pragma unroll
        for (int rg = 0; rg < 4; rg++)
          Vt[((h * HD) + d) * SEQ + mb + rg] = (bf16)acc[mq][nq][rg];
      } else {
        bf16* dst = kidx ? Kb : Qb;
#pragma unroll
        for (int rg = 0; rg < 4; rg++)
          dst[(h * SEQ + mb + rg) * HD + d] = (bf16)acc[mq][nq][rg];
      }
    }
  }
}

__global__ __launch_bounds__(256) void gemm_proj(
    const bf16* __restrict__ A, const bf16* __restrict__ B, float* __restrict__ C)
{
  __shared__ bf16 As[128][40];
  __shared__ bf16 Bs[128][40];
  const int m0 = blockIdx.x * 128, n0 = blockIdx.y * 128;
  f32x4 acc[4][4];
  gemm128_core(A, B, m0, n0, As, Bs, acc);

  const int lane = threadIdx.x & 63, w = threadIdx.x >> 6;
  const int c16 = lane & 15, q4 = lane >> 4;
  const int mo = (w & 1) * 64, no = (w >> 1) * 64;
#pragma unroll
  for (int nq = 0; nq < 4; nq++) {
    const int n = n0 + no + nq * 16 + c16;
#pragma unroll
    for (int mq = 0; mq < 4; mq++) {
      const int mb = m0 + mo + mq * 16 + q4 * 4;
#pragma unroll
      for (int rg = 0; rg < 4; rg++)
        C[(size_t)(mb + rg) * DM + n] = acc[mq][nq][rg];
    }
  }
}

// ---------------------------------------------------------------------------
__global__ __launch_bounds__(256) void norm_rope(bf16* __restrict__ Qb, bf16* __restrict__ Kb)
{
  const int row = blockIdx.x * 4 + (threadIdx.x >> 6);
  const int lane = threadIdx.x & 63;
  const bool isQ = row < NH * SEQ;
  bf16* base = isQ ? Qb : Kb;
  const int hr = isQ ? row : row - NH * SEQ;
  const int t = hr & (SEQ - 1);
  bf16* p = base + (size_t)hr * HD;

  float x = (float)p[lane];
  float ss = x * x;
#pragma unroll
  for (int off = 32; off; off >>= 1) ss += __shfl_xor(ss, off, 64);
  float xn = x * rsqrtf(ss * (1.0f / 64.0f) + RMS_EPS);
  float xp = __shfl_xor(xn, 32, 64);
  const int i = lane & 31;
  float fr = (i < 16) ? exp2f(-10.0f * (float)i * (1.0f / 15.0f)) : 0.0f;
  float th = (float)t * fr;
  float sn, cs;
  sincosf(th, &sn, &cs);
  float y = xn * cs + ((lane < 32) ? xp * sn : -xp * sn);
  if (isQ) y *= ATTN_SCALE;
  p[lane] = (bf16)y;
}

// ---------------------------------------------------------------------------
// Flash partial, barrier-free: fixed-scale softmax (|s| <= 7.68), K/V
// B-fragments direct from global (L1/L2), only wave-private Ps in LDS.
// Block = (qb, h, p); qi = 63-qb for LPT dispatch.
// ---------------------------------------------------------------------------
__global__ __launch_bounds__(256) void flash_partial(
    const bf16* __restrict__ Qb, const bf16* __restrict__ Kb,
    const bf16* __restrict__ Vt, float* __restrict__ Opart,
    float* __restrict__ Lpart)
{
  __shared__ bf16 Ps[4][16][72];
  const int h = blockIdx.y, p = blockIdx.z;
  const int qi = 63 - (int)blockIdx.x;            // heavy blocks dispatch first
  const int q0 = qi * 64;
  const int tid = threadIdx.x;
  const int lane = tid & 63, w = tid >> 6;
  const int c16 = lane & 15, q4 = lane >> 4;

  const int tq = q0 + w * 16 + c16;
  bf16x8 aq0 = *(const bf16x8*)&Qb[((h * SEQ) + tq) * HD + q4 * 8];
  bf16x8 aq1 = *(const bf16x8*)&Qb[((h * SEQ) + tq) * HD + 32 + q4 * 8];

  const f32x4 vzero = {0.f, 0.f, 0.f, 0.f};
  f32x4 O[4] = {vzero, vzero, vzero, vzero};
  float l_lane[4] = {0.f, 0.f, 0.f, 0.f};
  const int t_my0 = q0 + w * 16 + q4 * 4;
  const int safe_s0 = q0 + w * 16 - 63;           // s0 <= this => no mask needed

  const bf16* Kbase = Kb + (size_t)h * SEQ * HD;
  const bf16* Vbase = Vt + (size_t)h * HD * SEQ;

  for (int s0 = p * 64; s0 <= q0; s0 += NPART * 64) {
    // S = Q K^T; B-frags straight from global
    f32x4 S[4];
#pragma unroll
    for (int nt = 0; nt < 4; nt++) {
      const bf16* kp = &Kbase[(s0 + nt * 16 + c16) * HD + q4 * 8];
      bf16x8 b0 = *(const bf16x8*)kp;
      bf16x8 b1 = *(const bf16x8*)(kp + 32);
      f32x4 z = vzero;
      z = MFMA_BF16(aq0, b0, z);
      z = MFMA_BF16(aq1, b1, z);
      S[nt] = z;
    }
    // exp (no max shift) + lane-local l; mask only near the diagonal
    if (s0 <= safe_s0) {
#pragma unroll
      for (int nt = 0; nt < 4; nt++)
#pragma unroll
        for (int rg = 0; rg < 4; rg++) {
          const float pv = __expf(S[nt][rg]);
          S[nt][rg] = pv;
          l_lane[rg] += pv;
        }
    } else {
#pragma unroll
      for (int nt = 0; nt < 4; nt++) {
        const int s_g = s0 + nt * 16 + c16;
#pragma unroll
        for (int rg = 0; rg < 4; rg++) {
          const float pv = (s_g > t_my0 + rg) ? 0.f : __expf(S[nt][rg]);
          S[nt][rg] = pv;
          l_lane[rg] += pv;
        }
      }
    }
    // P: C-layout -> wave-private LDS -> A-layout
#pragma unroll
    for (int nt = 0; nt < 4; nt++)
#pragma unroll
      for (int rg = 0; rg < 4; rg++)
        Ps[w][q4 * 4 + rg][nt * 16 + c16] = (bf16)S[nt][rg];
    bf16x8 ap0 = *(const bf16x8*)&Ps[w][c16][q4 * 8];
    bf16x8 ap1 = *(const bf16x8*)&Ps[w][c16][32 + q4 * 8];
#pragma unroll
    for (int dt = 0; dt < 4; dt++) {
      const bf16* vp = &Vbase[(dt * 16 + c16) * SEQ + s0 + q4 * 8];
      bf16x8 bv0 = *(const bf16x8*)vp;
      bf16x8 bv1 = *(const bf16x8*)(vp + 32);
      O[dt] = MFMA_BF16(ap0, bv0, O[dt]);
      O[dt] = MFMA_BF16(ap1, bv1, O[dt]);
    }
  }
  // one l reduction at the end (16-lane row group)
#pragma unroll
  for (int rg = 0; rg < 4; rg++) {
    float l = l_lane[rg];
    l += __shfl_xor(l, 1, 64);
    l += __shfl_xor(l, 2, 64);
    l += __shfl_xor(l, 4, 64);
    l += __shfl_xor(l, 8, 64);
    l_lane[rg] = l;
  }
  const int u = ((h * 64 + qi) * NPART + p);
  float* Op = Opart + (size_t)u * 4096;
#pragma unroll
  for (int dt = 0; dt < 4; dt++)
#pragma unroll
    for (int rg = 0; rg < 4; rg++)
      Op[(w * 16 + q4 * 4 + rg) * 64 + dt * 16 + c16] = O[dt][rg];
  if (c16 == 0) {
#pragma unroll
    for (int rg = 0; rg < 4; rg++)
      Lpart[u * 64 + w * 16 + q4 * 4 + rg] = l_lane[rg];
  }
}

// ---------------------------------------------------------------------------
__global__ __launch_bounds__(256) void flash_combine(
    const float* __restrict__ Opart, const float* __restrict__ Lpart,
    bf16* __restrict__ Y)
{
  const int qi = blockIdx.x, h = blockIdx.y;
  const int row = threadIdx.x >> 2, cg = (threadIdx.x & 3) * 16;
  const int u0 = (h * 64 + qi) * NPART;
  const float inv = 1.0f / (Lpart[u0 * 64 + row] + Lpart[(u0 + 1) * 64 + row]);
  const float* O0 = Opart + (size_t)u0 * 4096 + row * 64 + cg;
  const float* O1 = O0 + 4096;
  bf16* yp = Y + (size_t)(qi * 64 + row) * DM + h * HD + cg;
#pragma unroll
  for (int j = 0; j < 16; j += 4) {
    f32x4 a = *(const f32x4*)(O0 + j);
    f32x4 b = *(const f32x4*)(O1 + j);
#pragma unroll
    for (int e = 0; e < 4; e++) yp[j + e] = (bf16)((a[e] + b[e]) * inv);
  }
}

// ---------------------------------------------------------------------------
extern "C" void kernel_launch(void* const* d_in, const int* in_sizes, int n_in,
                              void* d_out, int out_size, void* d_ws, size_t ws_size,
                              hipStream_t stream)
{
  (void)in_sizes; (void)n_in; (void)out_size; (void)ws_size;
  const float* x      = (const float*)d_in[0];
  const float* qkvw   = (const float*)d_in[1];
  const float* cprojw = (const float*)d_in[2];
  float* outp = (float*)d_out;

  const int NX = SEQ * DM, NW = NQKV * DM, NP = DM * DM;

  char* ws = (char*)d_ws;
  bf16*  xb    = (bf16*)(ws);                       // 6,291,456
  bf16*  wqkv  = (bf16*)(ws + 6291456);             // 3,538,944
  bf16*  wproj = (bf16*)(ws + 9830400);             // 1,179,648
  bf16*  Q     = (bf16*)(ws + 11010048);            // 6,291,456
  bf16*  K     = (bf16*)(ws + 17301504);            // 6,291,456
  bf16*  Vt    = (bf16*)(ws + 23592960);            // 6,291,456
  bf16*  Y     = (bf16*)(ws + 29884416);            // 6,291,456
  float* Opart = (float*)(ws + 36175872);           // 25,165,824
  float* Lpart = (float*)(ws + 61341696);           //    393,216  (total 61.7 MB)

  convert_in<<<dim3(NX / 2048), 256, 0, stream>>>(x,      xb,    NX);
  convert_in<<<dim3(NW / 2048), 256, 0, stream>>>(qkvw,   wqkv,  NW);
  convert_in<<<dim3(NP / 2048), 256, 0, stream>>>(cprojw, wproj, NP);

  gemm_qkv     <<<dim3(SEQ / 128, NQKV / 128), 256, 0, stream>>>(xb, wqkv, Q, K, Vt);
  norm_rope    <<<dim3(2 * NH * SEQ / 4),      256, 0, stream>>>(Q, K);
  flash_partial<<<dim3(SEQ / 64, NH, NPART),   256, 0, stream>>>(Q, K, Vt, Opart, Lpart);
  flash_combine<<<dim3(SEQ / 64, NH),          256, 0, stream>>>(Opart, Lpart, Y);
  gemm_proj    <<<dim3(SEQ / 128, DM / 128),   256, 0, stream>>>(Y, wproj, outp);
}

// Round 10
// 247.189 us; speedup vs baseline: 1.7580x; 1.7580x over previous
//
#include <hip/hip_runtime.h>
#include <math.h>

// Round 10: revert flash to R8 structure (LDS staging + fixed-scale softmax +
// register prefetch; R9's global-direct reads were a 2.7x regression — L2
// latency in the serial chain, 4x traffic). One change: NPART 2->4 for
// overlap (R8 ran at ~1.4 resident blocks/CU; per-iter latency chain was
// exposed). Opart stored bf16 to keep ws at the R8-proven 62 MB.

typedef __bf16 bf16;
typedef __bf16 bf16x8 __attribute__((ext_vector_type(8)));
typedef float  f32x4  __attribute__((ext_vector_type(4)));

#define MFMA_BF16(a, b, c) __builtin_amdgcn_mfma_f32_16x16x32_bf16((a), (b), (c), 0, 0, 0)

#define SEQ  4096
#define NH   12
#define HD   64
#define DM   768
#define NQKV 2304
#define NPART 4
#define ATTN_SCALE 0.12f
#define RMS_EPS 1.1920928955078125e-07f

// ---------------------------------------------------------------------------
__global__ __launch_bounds__(256) void convert_in(const float* __restrict__ src,
                                                  bf16* __restrict__ dst, int n)
{
  const int i0 = (blockIdx.x * 256 + threadIdx.x) * 8;
  if (i0 >= n) return;
  f32x4 a = *(const f32x4*)(src + i0);
  f32x4 b = *(const f32x4*)(src + i0 + 4);
  bf16x8 o;
#pragma unroll
  for (int j = 0; j < 4; j++) { o[j] = (bf16)a[j]; o[j + 4] = (bf16)b[j]; }
  *(bf16x8*)(dst + i0) = o;
}

// ---------------------------------------------------------------------------
// 128x128-tile GEMM core (BK=32, 4 waves in 2x2 quadrants of 64x64).
// ---------------------------------------------------------------------------
__device__ __forceinline__ void gemm128_core(
    const bf16* __restrict__ A, const bf16* __restrict__ B,
    int m0, int n0, bf16 (*As)[40], bf16 (*Bs)[40], f32x4 acc[4][4])
{
  const int tid = threadIdx.x;
  const int lane = tid & 63, w = tid >> 6;
  const int c16 = lane & 15, q4 = lane >> 4;
  const int mo = (w & 1) * 64, no = (w >> 1) * 64;
  const int srow = tid >> 2, scol = (tid & 3) * 8;
  const f32x4 vzero = {0.f, 0.f, 0.f, 0.f};
#pragma unroll
  for (int i = 0; i < 4; i++)
#pragma unroll
    for (int j = 0; j < 4; j++) acc[i][j] = vzero;

  for (int k0 = 0; k0 < DM; k0 += 32) {
#pragma unroll
    for (int ps = 0; ps < 2; ps++) {
      const int r = srow + ps * 64;
      *(bf16x8*)&As[r][scol] = *(const bf16x8*)&A[(m0 + r) * DM + k0 + scol];
      *(bf16x8*)&Bs[r][scol] = *(const bf16x8*)&B[(n0 + r) * DM + k0 + scol];
    }
    __syncthreads();
    bf16x8 ar[4], br[4];
#pragma unroll
    for (int mq = 0; mq < 4; mq++)
      ar[mq] = *(const bf16x8*)&As[mo + mq * 16 + c16][q4 * 8];
#pragma unroll
    for (int nq = 0; nq < 4; nq++)
      br[nq] = *(const bf16x8*)&Bs[no + nq * 16 + c16][q4 * 8];
#pragma unroll
    for (int mq = 0; mq < 4; mq++)
#pragma unroll
      for (int nq = 0; nq < 4; nq++)
        acc[mq][nq] = MFMA_BF16(ar[mq], br[nq], acc[mq][nq]);
    __syncthreads();
  }
}

__global__ __launch_bounds__(256) void gemm_qkv(
    const bf16* __restrict__ A, const bf16* __restrict__ B,
    bf16* __restrict__ Qb, bf16* __restrict__ Kb, bf16* __restrict__ Vt)
{
  __shared__ bf16 As[128][40];
  __shared__ bf16 Bs[128][40];
  const int m0 = blockIdx.x * 128, n0 = blockIdx.y * 128;
  f32x4 acc[4][4];
  gemm128_core(A, B, m0, n0, As, Bs, acc);

  const int lane = threadIdx.x & 63, w = threadIdx.x >> 6;
  const int c16 = lane & 15, q4 = lane >> 4;
  const int mo = (w & 1) * 64, no = (w >> 1) * 64;
  const int kidx = blockIdx.y / 6;
  const int rbase = n0 - kidx * DM;
#pragma unroll
  for (int nq = 0; nq < 4; nq++) {
    const int rr = rbase + no + nq * 16 + c16;
    const int h = rr >> 6, d = rr & 63;
#pragma unroll
    for (int mq = 0; mq < 4; mq++) {
      const int mb = m0 + mo + mq * 16 + q4 * 4;
      if (kidx == 2) {
#pragma unroll
        for (int rg = 0; rg < 4; rg++)
          Vt[((h * HD) + d) * SEQ + mb + rg] = (bf16)acc[mq][nq][rg];
      } else {
        bf16* dst = kidx ? Kb : Qb;
#pragma unroll
        for (int rg = 0; rg < 4; rg++)
          dst[(h * SEQ + mb + rg) * HD + d] = (bf16)acc[mq][nq][rg];
      }
    }
  }
}

__global__ __launch_bounds__(256) void gemm_proj(
    const bf16* __restrict__ A, const bf16* __restrict__ B, float* __restrict__ C)
{
  __shared__ bf16 As[128][40];
  __shared__ bf16 Bs[128][40];
  const int m0 = blockIdx.x * 128, n0 = blockIdx.y * 128;
  f32x4 acc[4][4];
  gemm128_core(A, B, m0, n0, As, Bs, acc);

  const int lane = threadIdx.x & 63, w = threadIdx.x >> 6;
  const int c16 = lane & 15, q4 = lane >> 4;
  const int mo = (w & 1) * 64, no = (w >> 1) * 64;
#pragma unroll
  for (int nq = 0; nq < 4; nq++) {
    const int n = n0 + no + nq * 16 + c16;
#pragma unroll
    for (int mq = 0; mq < 4; mq++) {
      const int mb = m0 + mo + mq * 16 + q4 * 4;
#pragma unroll
      for (int rg = 0; rg < 4; rg++)
        C[(size_t)(mb + rg) * DM + n] = acc[mq][nq][rg];
    }
  }
}

// ---------------------------------------------------------------------------
__global__ __launch_bounds__(256) void norm_rope(bf16* __restrict__ Qb, bf16* __restrict__ Kb)
{
  const int row = blockIdx.x * 4 + (threadIdx.x >> 6);
  const int lane = threadIdx.x & 63;
  const bool isQ = row < NH * SEQ;
  bf16* base = isQ ? Qb : Kb;
  const int hr = isQ ? row : row - NH * SEQ;
  const int t = hr & (SEQ - 1);
  bf16* p = base + (size_t)hr * HD;

  float x = (float)p[lane];
  float ss = x * x;
#pragma unroll
  for (int off = 32; off; off >>= 1) ss += __shfl_xor(ss, off, 64);
  float xn = x * rsqrtf(ss * (1.0f / 64.0f) + RMS_EPS);
  float xp = __shfl_xor(xn, 32, 64);
  const int i = lane & 31;
  float fr = (i < 16) ? exp2f(-10.0f * (float)i * (1.0f / 15.0f)) : 0.0f;
  float th = (float)t * fr;
  float sn, cs;
  sincosf(th, &sn, &cs);
  float y = xn * cs + ((lane < 32) ? xp * sn : -xp * sn);
  if (isQ) y *= ATTN_SCALE;
  p[lane] = (bf16)y;
}

// ---------------------------------------------------------------------------
// Flash partial (R8 structure): LDS-staged K/V tiles, fixed-scale softmax
// (|s| <= 0.12*8*8 = 7.68 by Cauchy-Schwarz -> exp w/o max shift), register
// prefetch of next tile, zero cross-lane ops in the loop. NPART=4 split-K.
// ---------------------------------------------------------------------------
__global__ __launch_bounds__(256) void flash_partial(
    const bf16* __restrict__ Qb, const bf16* __restrict__ Kb,
    const bf16* __restrict__ Vt, bf16* __restrict__ Opart,
    float* __restrict__ Lpart)
{
  __shared__ bf16 Ks[64][72];
  __shared__ bf16 Vts[64][72];
  __shared__ bf16 Ps[4][16][72];
  const int h = blockIdx.y, p = blockIdx.z;
  const int qb = blockIdx.x;
  const int qi = (qb & 1) ? (63 - (qb >> 1)) : (qb >> 1);  // light/heavy pairing
  const int q0 = qi * 64;
  const int tid = threadIdx.x;
  const int lane = tid & 63, w = tid >> 6;
  const int c16 = lane & 15, q4 = lane >> 4;
  const int sr = tid >> 3, sc8 = (tid & 7) * 8;

  const int tq = q0 + w * 16 + c16;
  bf16x8 aq0 = *(const bf16x8*)&Qb[((h * SEQ) + tq) * HD + q4 * 8];
  bf16x8 aq1 = *(const bf16x8*)&Qb[((h * SEQ) + tq) * HD + 32 + q4 * 8];

  const f32x4 vzero = {0.f, 0.f, 0.f, 0.f};
  f32x4 O[4] = {vzero, vzero, vzero, vzero};
  float l_lane[4] = {0.f, 0.f, 0.f, 0.f};
  const int t_my0 = q0 + w * 16 + q4 * 4;

  const bf16* Kbase = Kb + (size_t)h * SEQ * HD;
  const bf16* Vbase = Vt + (size_t)h * HD * SEQ;

  const int sBeg = p * 64;
  if (sBeg <= q0) {
    bf16x8 kr0 = *(const bf16x8*)&Kbase[(sBeg + sr) * HD + sc8];
    bf16x8 kr1 = *(const bf16x8*)&Kbase[(sBeg + sr + 32) * HD + sc8];
    bf16x8 vr0 = *(const bf16x8*)&Vbase[sr * SEQ + sBeg + sc8];
    bf16x8 vr1 = *(const bf16x8*)&Vbase[(sr + 32) * SEQ + sBeg + sc8];

    for (int s0 = sBeg; s0 <= q0; s0 += NPART * 64) {
      __syncthreads();
      *(bf16x8*)&Ks[sr][sc8]       = kr0;
      *(bf16x8*)&Ks[sr + 32][sc8]  = kr1;
      *(bf16x8*)&Vts[sr][sc8]      = vr0;
      *(bf16x8*)&Vts[sr + 32][sc8] = vr1;
      __syncthreads();

      const int snext = s0 + NPART * 64;
      if (snext <= q0) {
        kr0 = *(const bf16x8*)&Kbase[(snext + sr) * HD + sc8];
        kr1 = *(const bf16x8*)&Kbase[(snext + sr + 32) * HD + sc8];
        vr0 = *(const bf16x8*)&Vbase[sr * SEQ + snext + sc8];
        vr1 = *(const bf16x8*)&Vbase[(sr + 32) * SEQ + snext + sc8];
      }

      f32x4 S[4];
#pragma unroll
      for (int nt = 0; nt < 4; nt++) {
        bf16x8 b0 = *(const bf16x8*)&Ks[nt * 16 + c16][q4 * 8];
        bf16x8 b1 = *(const bf16x8*)&Ks[nt * 16 + c16][32 + q4 * 8];
        f32x4 z = vzero;
        z = MFMA_BF16(aq0, b0, z);
        z = MFMA_BF16(aq1, b1, z);
        S[nt] = z;
      }
#pragma unroll
      for (int nt = 0; nt < 4; nt++) {
        const int s_g = s0 + nt * 16 + c16;
#pragma unroll
        for (int rg = 0; rg < 4; rg++) {
          const float pv = (s_g > t_my0 + rg) ? 0.f : __expf(S[nt][rg]);
          S[nt][rg] = pv;
          l_lane[rg] += pv;
        }
      }
#pragma unroll
      for (int nt = 0; nt < 4; nt++)
#pragma unroll
        for (int rg = 0; rg < 4; rg++)
          Ps[w][q4 * 4 + rg][nt * 16 + c16] = (bf16)S[nt][rg];
      bf16x8 ap0 = *(const bf16x8*)&Ps[w][c16][q4 * 8];
      bf16x8 ap1 = *(const bf16x8*)&Ps[w][c16][32 + q4 * 8];
#pragma unroll
      for (int dt = 0; dt < 4; dt++) {
        bf16x8 bv0 = *(const bf16x8*)&Vts[dt * 16 + c16][q4 * 8];
        bf16x8 bv1 = *(const bf16x8*)&Vts[dt * 16 + c16][32 + q4 * 8];
        O[dt] = MFMA_BF16(ap0, bv0, O[dt]);
        O[dt] = MFMA_BF16(ap1, bv1, O[dt]);
      }
    }
  }
#pragma unroll
  for (int rg = 0; rg < 4; rg++) {
    float l = l_lane[rg];
    l += __shfl_xor(l, 1, 64);
    l += __shfl_xor(l, 2, 64);
    l += __shfl_xor(l, 4, 64);
    l += __shfl_xor(l, 8, 64);
    l_lane[rg] = l;
  }
  const int u = ((h * 64 + qi) * NPART + p);
  bf16* Op = Opart + (size_t)u * 4096;
#pragma unroll
  for (int dt = 0; dt < 4; dt++)
#pragma unroll
    for (int rg = 0; rg < 4; rg++)
      Op[(w * 16 + q4 * 4 + rg) * 64 + dt * 16 + c16] = (bf16)O[dt][rg];
  if (c16 == 0) {
#pragma unroll
    for (int rg = 0; rg < 4; rg++)
      Lpart[u * 64 + w * 16 + q4 * 4 + rg] = l_lane[rg];
  }
}

// ---------------------------------------------------------------------------
// Combine: Y = (sum_p O_p) / (sum_p l_p), 4 bf16 partials, fp32 accumulate.
// ---------------------------------------------------------------------------
__global__ __launch_bounds__(256) void flash_combine(
    const bf16* __restrict__ Opart, const float* __restrict__ Lpart,
    bf16* __restrict__ Y)
{
  const int qi = blockIdx.x, h = blockIdx.y;
  const int row = threadIdx.x >> 2, cg = (threadIdx.x & 3) * 16;
  const int u0 = (h * 64 + qi) * NPART;
  float lsum = 0.f;
#pragma unroll
  for (int p = 0; p < NPART; p++) lsum += Lpart[(u0 + p) * 64 + row];
  const float inv = 1.0f / lsum;
  const bf16* O0 = Opart + (size_t)u0 * 4096 + row * 64 + cg;
  bf16* yp = Y + (size_t)(qi * 64 + row) * DM + h * HD + cg;
#pragma unroll
  for (int j = 0; j < 16; j += 8) {
    float s[8] = {0, 0, 0, 0, 0, 0, 0, 0};
#pragma unroll
    for (int p = 0; p < NPART; p++) {
      bf16x8 a = *(const bf16x8*)(O0 + p * 4096 + j);
#pragma unroll
      for (int e = 0; e < 8; e++) s[e] += (float)a[e];
    }
#pragma unroll
    for (int e = 0; e < 8; e++) yp[j + e] = (bf16)(s[e] * inv);
  }
}

// ---------------------------------------------------------------------------
extern "C" void kernel_launch(void* const* d_in, const int* in_sizes, int n_in,
                              void* d_out, int out_size, void* d_ws, size_t ws_size,
                              hipStream_t stream)
{
  (void)in_sizes; (void)n_in; (void)out_size; (void)ws_size;
  const float* x      = (const float*)d_in[0];
  const float* qkvw   = (const float*)d_in[1];
  const float* cprojw = (const float*)d_in[2];
  float* outp = (float*)d_out;

  const int NX = SEQ * DM, NW = NQKV * DM, NP = DM * DM;

  char* ws = (char*)d_ws;
  bf16*  xb    = (bf16*)(ws);                       // 6,291,456
  bf16*  wqkv  = (bf16*)(ws + 6291456);             // 3,538,944
  bf16*  wproj = (bf16*)(ws + 9830400);             // 1,179,648
  bf16*  Q     = (bf16*)(ws + 11010048);            // 6,291,456
  bf16*  K     = (bf16*)(ws + 17301504);            // 6,291,456
  bf16*  Vt    = (bf16*)(ws + 23592960);            // 6,291,456
  bf16*  Y     = (bf16*)(ws + 29884416);            // 6,291,456
  bf16*  Opart = (bf16*)(ws + 36175872);            // 25,165,824 (bf16, NPART=4)
  float* Lpart = (float*)(ws + 61341696);           //    786,432  (total 62.1 MB)

  convert_in<<<dim3(NX / 2048), 256, 0, stream>>>(x,      xb,    NX);
  convert_in<<<dim3(NW / 2048), 256, 0, stream>>>(qkvw,   wqkv,  NW);
  convert_in<<<dim3(NP / 2048), 256, 0, stream>>>(cprojw, wproj, NP);

  gemm_qkv     <<<dim3(SEQ / 128, NQKV / 128), 256, 0, stream>>>(xb, wqkv, Q, K, Vt);
  norm_rope    <<<dim3(2 * NH * SEQ / 4),      256, 0, stream>>>(Q, K);
  flash_partial<<<dim3(SEQ / 64, NH, NPART),   256, 0, stream>>>(Q, K, Vt, Opart, Lpart);
  flash_combine<<<dim3(SEQ / 64, NH),          256, 0, stream>>>(Opart, Lpart, Y);
  gemm_proj    <<<dim3(SEQ / 128, DM / 128),   256, 0, stream>>>(Y, wproj, outp);
}

// Round 11
// 221.592 us; speedup vs baseline: 1.9611x; 1.1155x over previous
//
#include <hip/hip_runtime.h>
#include <math.h>

// Round 11: (1) flash BM=128 q-blocks — 2x MFMA per staged K/V tile, half the
// iterations (the m92->m93 move applied to flash; R10 proved the 64-tile
// structure plateaus at ~260 TF). (2) norm+rope fused into gemm_qkv epilogue
// (wave quadrant = one head; rotary partner d^32 is lane-local nq^2; one
// sincos per row). norm_rope kernel deleted.

typedef __bf16 bf16;
typedef __bf16 bf16x8 __attribute__((ext_vector_type(8)));
typedef float  f32x4  __attribute__((ext_vector_type(4)));

#define MFMA_BF16(a, b, c) __builtin_amdgcn_mfma_f32_16x16x32_bf16((a), (b), (c), 0, 0, 0)

#define SEQ  4096
#define NH   12
#define HD   64
#define DM   768
#define NQKV 2304
#define NPART 4
#define ATTN_SCALE 0.12f
#define RMS_EPS 1.1920928955078125e-07f

// ---------------------------------------------------------------------------
__global__ __launch_bounds__(256) void convert_in(const float* __restrict__ src,
                                                  bf16* __restrict__ dst, int n)
{
  const int i0 = (blockIdx.x * 256 + threadIdx.x) * 8;
  if (i0 >= n) return;
  f32x4 a = *(const f32x4*)(src + i0);
  f32x4 b = *(const f32x4*)(src + i0 + 4);
  bf16x8 o;
#pragma unroll
  for (int j = 0; j < 4; j++) { o[j] = (bf16)a[j]; o[j + 4] = (bf16)b[j]; }
  *(bf16x8*)(dst + i0) = o;
}

// ---------------------------------------------------------------------------
// 128x128-tile GEMM core (BK=32, 4 waves in 2x2 quadrants of 64x64).
// ---------------------------------------------------------------------------
__device__ __forceinline__ void gemm128_core(
    const bf16* __restrict__ A, const bf16* __restrict__ B,
    int m0, int n0, bf16 (*As)[40], bf16 (*Bs)[40], f32x4 acc[4][4])
{
  const int tid = threadIdx.x;
  const int lane = tid & 63, w = tid >> 6;
  const int c16 = lane & 15, q4 = lane >> 4;
  const int mo = (w & 1) * 64, no = (w >> 1) * 64;
  const int srow = tid >> 2, scol = (tid & 3) * 8;
  const f32x4 vzero = {0.f, 0.f, 0.f, 0.f};
#pragma unroll
  for (int i = 0; i < 4; i++)
#pragma unroll
    for (int j = 0; j < 4; j++) acc[i][j] = vzero;

  for (int k0 = 0; k0 < DM; k0 += 32) {
#pragma unroll
    for (int ps = 0; ps < 2; ps++) {
      const int r = srow + ps * 64;
      *(bf16x8*)&As[r][scol] = *(const bf16x8*)&A[(m0 + r) * DM + k0 + scol];
      *(bf16x8*)&Bs[r][scol] = *(const bf16x8*)&B[(n0 + r) * DM + k0 + scol];
    }
    __syncthreads();
    bf16x8 ar[4], br[4];
#pragma unroll
    for (int mq = 0; mq < 4; mq++)
      ar[mq] = *(const bf16x8*)&As[mo + mq * 16 + c16][q4 * 8];
#pragma unroll
    for (int nq = 0; nq < 4; nq++)
      br[nq] = *(const bf16x8*)&Bs[no + nq * 16 + c16][q4 * 8];
#pragma unroll
    for (int mq = 0; mq < 4; mq++)
#pragma unroll
      for (int nq = 0; nq < 4; nq++)
        acc[mq][nq] = MFMA_BF16(ar[mq], br[nq], acc[mq][nq]);
    __syncthreads();
  }
}

// QKV GEMM with FUSED norm+rope epilogue for Q/K (V written transposed raw).
__global__ __launch_bounds__(256) void gemm_qkv(
    const bf16* __restrict__ A, const bf16* __restrict__ B,
    bf16* __restrict__ Qb, bf16* __restrict__ Kb, bf16* __restrict__ Vt)
{
  __shared__ bf16 As[128][40];
  __shared__ bf16 Bs[128][40];
  const int m0 = blockIdx.x * 128, n0 = blockIdx.y * 128;
  f32x4 acc[4][4];
  gemm128_core(A, B, m0, n0, As, Bs, acc);

  const int lane = threadIdx.x & 63, w = threadIdx.x >> 6;
  const int c16 = lane & 15, q4 = lane >> 4;
  const int mo = (w & 1) * 64, no = (w >> 1) * 64;
  const int kidx = blockIdx.y / 6;
  const int rr0 = (n0 - kidx * DM) + no;     // multiple of 64: one full head
  const int h = rr0 >> 6;

  if (kidx == 2) {
#pragma unroll
    for (int nq = 0; nq < 4; nq++) {
      const int d = nq * 16 + c16;
#pragma unroll
      for (int mq = 0; mq < 4; mq++) {
        const int mb = m0 + mo + mq * 16 + q4 * 4;
#pragma unroll
        for (int rg = 0; rg < 4; rg++)
          Vt[((h * HD) + d) * SEQ + mb + rg] = (bf16)acc[mq][nq][rg];
      }
    }
  } else {
    bf16* dst = kidx ? Kb : Qb;
    const float scale = kidx ? 1.0f : ATTN_SCALE;
    const float fr = exp2f(-10.0f * (float)c16 * (1.0f / 15.0f));
#pragma unroll
    for (int mq = 0; mq < 4; mq++) {
#pragma unroll
      for (int rg = 0; rg < 4; rg++) {
        const int m = m0 + mo + mq * 16 + q4 * 4 + rg;
        const float x0 = acc[mq][0][rg], x1 = acc[mq][1][rg];
        const float x2 = acc[mq][2][rg], x3 = acc[mq][3][rg];
        float ss = x0 * x0 + x1 * x1 + x2 * x2 + x3 * x3;
        ss += __shfl_xor(ss, 1, 64);
        ss += __shfl_xor(ss, 2, 64);
        ss += __shfl_xor(ss, 4, 64);
        ss += __shfl_xor(ss, 8, 64);
        const float rinv = rsqrtf(ss * (1.0f / 64.0f) + RMS_EPS) * scale;
        const float xn0 = x0 * rinv, xn1 = x1 * rinv;
        const float xn2 = x2 * rinv, xn3 = x3 * rinv;
        float sn, cs;
        sincosf((float)m * fr, &sn, &cs);
        // d=c16 (nq0) pairs with d+32 (nq2), freq i=c16; nq1/nq3 have i>=16 -> identity
        const float y0 = xn0 * cs + xn2 * sn;
        const float y2 = xn2 * cs - xn0 * sn;
        bf16* rp = dst + (size_t)(h * SEQ + m) * HD + c16;
        rp[0]  = (bf16)y0;
        rp[16] = (bf16)xn1;
        rp[32] = (bf16)y2;
        rp[48] = (bf16)xn3;
      }
    }
  }
}

__global__ __launch_bounds__(256) void gemm_proj(
    const bf16* __restrict__ A, const bf16* __restrict__ B, float* __restrict__ C)
{
  __shared__ bf16 As[128][40];
  __shared__ bf16 Bs[128][40];
  const int m0 = blockIdx.x * 128, n0 = blockIdx.y * 128;
  f32x4 acc[4][4];
  gemm128_core(A, B, m0, n0, As, Bs, acc);

  const int lane = threadIdx.x & 63, w = threadIdx.x >> 6;
  const int c16 = lane & 15, q4 = lane >> 4;
  const int mo = (w & 1) * 64, no = (w >> 1) * 64;
#pragma unroll
  for (int nq = 0; nq < 4; nq++) {
    const int n = n0 + no + nq * 16 + c16;
#pragma unroll
    for (int mq = 0; mq < 4; mq++) {
      const int mb = m0 + mo + mq * 16 + q4 * 4;
#pragma unroll
      for (int rg = 0; rg < 4; rg++)
        C[(size_t)(mb + rg) * DM + n] = acc[mq][nq][rg];
    }
  }
}

// ---------------------------------------------------------------------------
// Flash partial, BM=128: block = (qb in 0..31, h, p). Each wave owns 32 rows
// (2 A-fragments). K/V tile (64 s) staged once serves 128 MFMA/block-iter.
// Fixed-scale softmax (|s| <= 7.68), register prefetch, NPART=4 split-K.
// ---------------------------------------------------------------------------
__global__ __launch_bounds__(256) void flash_partial(
    const bf16* __restrict__ Qb, const bf16* __restrict__ Kb,
    const bf16* __restrict__ Vt, bf16* __restrict__ Opart,
    float* __restrict__ Lpart)
{
  __shared__ bf16 Ks[64][72];
  __shared__ bf16 Vts[64][72];
  __shared__ bf16 Ps[4][32][72];
  const int h = blockIdx.y, p = blockIdx.z;
  const int qi = 31 - (int)blockIdx.x;            // LPT: heavy blocks first
  const int q0 = qi * 128;
  const int tid = threadIdx.x;
  const int lane = tid & 63, w = tid >> 6;
  const int c16 = lane & 15, q4 = lane >> 4;
  const int sr = tid >> 3, sc8 = (tid & 7) * 8;

  bf16x8 aq[2][2];
#pragma unroll
  for (int f = 0; f < 2; f++) {
    const int tq = q0 + w * 32 + f * 16 + c16;
    aq[f][0] = *(const bf16x8*)&Qb[((h * SEQ) + tq) * HD + q4 * 8];
    aq[f][1] = *(const bf16x8*)&Qb[((h * SEQ) + tq) * HD + 32 + q4 * 8];
  }

  const f32x4 vzero = {0.f, 0.f, 0.f, 0.f};
  f32x4 O[2][4];
  float l_lane[2][4];
#pragma unroll
  for (int f = 0; f < 2; f++)
#pragma unroll
    for (int j = 0; j < 4; j++) { O[f][j] = vzero; l_lane[f][j] = 0.f; }
  const int t_my0[2] = { q0 + w * 32 + q4 * 4, q0 + w * 32 + 16 + q4 * 4 };

  const bf16* Kbase = Kb + (size_t)h * SEQ * HD;
  const bf16* Vbase = Vt + (size_t)h * HD * SEQ;

  const int sEnd = q0 + 64;                       // last valid s-tile start
  const int sBeg = p * 64;
  if (sBeg <= sEnd) {
    bf16x8 kr0 = *(const bf16x8*)&Kbase[(sBeg + sr) * HD + sc8];
    bf16x8 kr1 = *(const bf16x8*)&Kbase[(sBeg + sr + 32) * HD + sc8];
    bf16x8 vr0 = *(const bf16x8*)&Vbase[sr * SEQ + sBeg + sc8];
    bf16x8 vr1 = *(const bf16x8*)&Vbase[(sr + 32) * SEQ + sBeg + sc8];

    for (int s0 = sBeg; s0 <= sEnd; s0 += NPART * 64) {
      __syncthreads();
      *(bf16x8*)&Ks[sr][sc8]       = kr0;
      *(bf16x8*)&Ks[sr + 32][sc8]  = kr1;
      *(bf16x8*)&Vts[sr][sc8]      = vr0;
      *(bf16x8*)&Vts[sr + 32][sc8] = vr1;
      __syncthreads();

      const int snext = s0 + NPART * 64;
      if (snext <= sEnd) {
        kr0 = *(const bf16x8*)&Kbase[(snext + sr) * HD + sc8];
        kr1 = *(const bf16x8*)&Kbase[(snext + sr + 32) * HD + sc8];
        vr0 = *(const bf16x8*)&Vbase[sr * SEQ + snext + sc8];
        vr1 = *(const bf16x8*)&Vbase[(sr + 32) * SEQ + snext + sc8];
      }

#pragma unroll
      for (int f = 0; f < 2; f++) {
        f32x4 S[4];
#pragma unroll
        for (int nt = 0; nt < 4; nt++) {
          bf16x8 b0 = *(const bf16x8*)&Ks[nt * 16 + c16][q4 * 8];
          bf16x8 b1 = *(const bf16x8*)&Ks[nt * 16 + c16][32 + q4 * 8];
          f32x4 z = vzero;
          z = MFMA_BF16(aq[f][0], b0, z);
          z = MFMA_BF16(aq[f][1], b1, z);
          S[nt] = z;
        }
#pragma unroll
        for (int nt = 0; nt < 4; nt++) {
          const int s_g = s0 + nt * 16 + c16;
#pragma unroll
          for (int rg = 0; rg < 4; rg++) {
            const float pv = (s_g > t_my0[f] + rg) ? 0.f : __expf(S[nt][rg]);
            S[nt][rg] = pv;
            l_lane[f][rg] += pv;
          }
        }
#pragma unroll
        for (int nt = 0; nt < 4; nt++)
#pragma unroll
          for (int rg = 0; rg < 4; rg++)
            Ps[w][f * 16 + q4 * 4 + rg][nt * 16 + c16] = (bf16)S[nt][rg];
      }
      // PV: V-fragments read once, used for both row-fragments
      bf16x8 ap[2][2];
#pragma unroll
      for (int f = 0; f < 2; f++) {
        ap[f][0] = *(const bf16x8*)&Ps[w][f * 16 + c16][q4 * 8];
        ap[f][1] = *(const bf16x8*)&Ps[w][f * 16 + c16][32 + q4 * 8];
      }
#pragma unroll
      for (int dt = 0; dt < 4; dt++) {
        bf16x8 bv0 = *(const bf16x8*)&Vts[dt * 16 + c16][q4 * 8];
        bf16x8 bv1 = *(const bf16x8*)&Vts[dt * 16 + c16][32 + q4 * 8];
#pragma unroll
        for (int f = 0; f < 2; f++) {
          O[f][dt] = MFMA_BF16(ap[f][0], bv0, O[f][dt]);
          O[f][dt] = MFMA_BF16(ap[f][1], bv1, O[f][dt]);
        }
      }
    }
  }
#pragma unroll
  for (int f = 0; f < 2; f++)
#pragma unroll
    for (int rg = 0; rg < 4; rg++) {
      float l = l_lane[f][rg];
      l += __shfl_xor(l, 1, 64);
      l += __shfl_xor(l, 2, 64);
      l += __shfl_xor(l, 4, 64);
      l += __shfl_xor(l, 8, 64);
      l_lane[f][rg] = l;
    }
  const int u = ((h * 32 + qi) * NPART + p);
  bf16* Op = Opart + (size_t)u * 8192;            // 128 x 64
#pragma unroll
  for (int f = 0; f < 2; f++)
#pragma unroll
    for (int dt = 0; dt < 4; dt++)
#pragma unroll
      for (int rg = 0; rg < 4; rg++)
        Op[(w * 32 + f * 16 + q4 * 4 + rg) * 64 + dt * 16 + c16] = (bf16)O[f][dt][rg];
  if (c16 == 0) {
#pragma unroll
    for (int f = 0; f < 2; f++)
#pragma unroll
      for (int rg = 0; rg < 4; rg++)
        Lpart[u * 128 + w * 32 + f * 16 + q4 * 4 + rg] = l_lane[f][rg];
  }
}

// ---------------------------------------------------------------------------
// Combine: Y = (sum_p O_p) / (sum_p l_p). Block per 64-row chunk x head.
// ---------------------------------------------------------------------------
__global__ __launch_bounds__(256) void flash_combine(
    const bf16* __restrict__ Opart, const float* __restrict__ Lpart,
    bf16* __restrict__ Y)
{
  const int q64 = blockIdx.x, h = blockIdx.y;
  const int qi = q64 >> 1, roff = (q64 & 1) * 64;
  const int row = threadIdx.x >> 2, cg = (threadIdx.x & 3) * 16;
  const int u0 = (h * 32 + qi) * NPART;
  const int r128 = roff + row;
  float lsum = 0.f;
#pragma unroll
  for (int p = 0; p < NPART; p++) lsum += Lpart[(u0 + p) * 128 + r128];
  const float inv = 1.0f / lsum;
  const bf16* O0 = Opart + (size_t)u0 * 8192 + r128 * 64 + cg;
  bf16* yp = Y + (size_t)(q64 * 64 + row) * DM + h * HD + cg;
#pragma unroll
  for (int j = 0; j < 16; j += 8) {
    float s[8] = {0, 0, 0, 0, 0, 0, 0, 0};
#pragma unroll
    for (int p = 0; p < NPART; p++) {
      bf16x8 a = *(const bf16x8*)(O0 + p * 8192 + j);
#pragma unroll
      for (int e = 0; e < 8; e++) s[e] += (float)a[e];
    }
#pragma unroll
    for (int e = 0; e < 8; e++) yp[j + e] = (bf16)(s[e] * inv);
  }
}

// ---------------------------------------------------------------------------
extern "C" void kernel_launch(void* const* d_in, const int* in_sizes, int n_in,
                              void* d_out, int out_size, void* d_ws, size_t ws_size,
                              hipStream_t stream)
{
  (void)in_sizes; (void)n_in; (void)out_size; (void)ws_size;
  const float* x      = (const float*)d_in[0];
  const float* qkvw   = (const float*)d_in[1];
  const float* cprojw = (const float*)d_in[2];
  float* outp = (float*)d_out;

  const int NX = SEQ * DM, NW = NQKV * DM, NP = DM * DM;

  char* ws = (char*)d_ws;
  bf16*  xb    = (bf16*)(ws);                       // 6,291,456
  bf16*  wqkv  = (bf16*)(ws + 6291456);             // 3,538,944
  bf16*  wproj = (bf16*)(ws + 9830400);             // 1,179,648
  bf16*  Q     = (bf16*)(ws + 11010048);            // 6,291,456
  bf16*  K     = (bf16*)(ws + 17301504);            // 6,291,456
  bf16*  Vt    = (bf16*)(ws + 23592960);            // 6,291,456
  bf16*  Y     = (bf16*)(ws + 29884416);            // 6,291,456
  bf16*  Opart = (bf16*)(ws + 36175872);            // 25,165,824 (1536 x 8192 bf16)
  float* Lpart = (float*)(ws + 61341696);           //    786,432  (total 62.1 MB)

  convert_in<<<dim3(NX / 2048), 256, 0, stream>>>(x,      xb,    NX);
  convert_in<<<dim3(NW / 2048), 256, 0, stream>>>(qkvw,   wqkv,  NW);
  convert_in<<<dim3(NP / 2048), 256, 0, stream>>>(cprojw, wproj, NP);

  gemm_qkv     <<<dim3(SEQ / 128, NQKV / 128), 256, 0, stream>>>(xb, wqkv, Q, K, Vt);
  flash_partial<<<dim3(SEQ / 128, NH, NPART),  256, 0, stream>>>(Q, K, Vt, Opart, Lpart);
  flash_combine<<<dim3(SEQ / 64, NH),          256, 0, stream>>>(Opart, Lpart, Y);
  gemm_proj    <<<dim3(SEQ / 128, DM / 128),   256, 0, stream>>>(Y, wproj, outp);
}

// Round 12
// 212.726 us; speedup vs baseline: 2.0428x; 1.0417x over previous
//
#include <hip/hip_runtime.h>
#include <math.h>

// Round 12: flash inner loop recast as S^T = MFMA(K_frag, Q_frag) (A/B lane
// layouts are identical, m89). Payoff: P round-trip becomes vectorized both
// ways (b64 writes / b128 reads via Pst[q][s], stride 68 = conflict-free
// 8B pairs), K-fragments hoisted out of the f-loop (read once). LDS-unit
// cycles/iter ~2280 -> ~1280. Everything else unchanged from R11.

typedef __bf16 bf16;
typedef __bf16 bf16x4 __attribute__((ext_vector_type(4)));
typedef __bf16 bf16x8 __attribute__((ext_vector_type(8)));
typedef float  f32x4  __attribute__((ext_vector_type(4)));

#define MFMA_BF16(a, b, c) __builtin_amdgcn_mfma_f32_16x16x32_bf16((a), (b), (c), 0, 0, 0)

#define SEQ  4096
#define NH   12
#define HD   64
#define DM   768
#define NQKV 2304
#define NPART 4
#define ATTN_SCALE 0.12f
#define RMS_EPS 1.1920928955078125e-07f

// ---------------------------------------------------------------------------
__global__ __launch_bounds__(256) void convert_in(const float* __restrict__ src,
                                                  bf16* __restrict__ dst, int n)
{
  const int i0 = (blockIdx.x * 256 + threadIdx.x) * 8;
  if (i0 >= n) return;
  f32x4 a = *(const f32x4*)(src + i0);
  f32x4 b = *(const f32x4*)(src + i0 + 4);
  bf16x8 o;
#pragma unroll
  for (int j = 0; j < 4; j++) { o[j] = (bf16)a[j]; o[j + 4] = (bf16)b[j]; }
  *(bf16x8*)(dst + i0) = o;
}

// ---------------------------------------------------------------------------
// 128x128-tile GEMM core (BK=32, 4 waves in 2x2 quadrants of 64x64).
// ---------------------------------------------------------------------------
__device__ __forceinline__ void gemm128_core(
    const bf16* __restrict__ A, const bf16* __restrict__ B,
    int m0, int n0, bf16 (*As)[40], bf16 (*Bs)[40], f32x4 acc[4][4])
{
  const int tid = threadIdx.x;
  const int lane = tid & 63, w = tid >> 6;
  const int c16 = lane & 15, q4 = lane >> 4;
  const int mo = (w & 1) * 64, no = (w >> 1) * 64;
  const int srow = tid >> 2, scol = (tid & 3) * 8;
  const f32x4 vzero = {0.f, 0.f, 0.f, 0.f};
#pragma unroll
  for (int i = 0; i < 4; i++)
#pragma unroll
    for (int j = 0; j < 4; j++) acc[i][j] = vzero;

  for (int k0 = 0; k0 < DM; k0 += 32) {
#pragma unroll
    for (int ps = 0; ps < 2; ps++) {
      const int r = srow + ps * 64;
      *(bf16x8*)&As[r][scol] = *(const bf16x8*)&A[(m0 + r) * DM + k0 + scol];
      *(bf16x8*)&Bs[r][scol] = *(const bf16x8*)&B[(n0 + r) * DM + k0 + scol];
    }
    __syncthreads();
    bf16x8 ar[4], br[4];
#pragma unroll
    for (int mq = 0; mq < 4; mq++)
      ar[mq] = *(const bf16x8*)&As[mo + mq * 16 + c16][q4 * 8];
#pragma unroll
    for (int nq = 0; nq < 4; nq++)
      br[nq] = *(const bf16x8*)&Bs[no + nq * 16 + c16][q4 * 8];
#pragma unroll
    for (int mq = 0; mq < 4; mq++)
#pragma unroll
      for (int nq = 0; nq < 4; nq++)
        acc[mq][nq] = MFMA_BF16(ar[mq], br[nq], acc[mq][nq]);
    __syncthreads();
  }
}

// QKV GEMM with FUSED norm+rope epilogue for Q/K (V written transposed raw).
__global__ __launch_bounds__(256) void gemm_qkv(
    const bf16* __restrict__ A, const bf16* __restrict__ B,
    bf16* __restrict__ Qb, bf16* __restrict__ Kb, bf16* __restrict__ Vt)
{
  __shared__ bf16 As[128][40];
  __shared__ bf16 Bs[128][40];
  const int m0 = blockIdx.x * 128, n0 = blockIdx.y * 128;
  f32x4 acc[4][4];
  gemm128_core(A, B, m0, n0, As, Bs, acc);

  const int lane = threadIdx.x & 63, w = threadIdx.x >> 6;
  const int c16 = lane & 15, q4 = lane >> 4;
  const int mo = (w & 1) * 64, no = (w >> 1) * 64;
  const int kidx = blockIdx.y / 6;
  const int rr0 = (n0 - kidx * DM) + no;     // multiple of 64: one full head
  const int h = rr0 >> 6;

  if (kidx == 2) {
#pragma unroll
    for (int nq = 0; nq < 4; nq++) {
      const int d = nq * 16 + c16;
#pragma unroll
      for (int mq = 0; mq < 4; mq++) {
        const int mb = m0 + mo + mq * 16 + q4 * 4;
#pragma unroll
        for (int rg = 0; rg < 4; rg++)
          Vt[((h * HD) + d) * SEQ + mb + rg] = (bf16)acc[mq][nq][rg];
      }
    }
  } else {
    bf16* dst = kidx ? Kb : Qb;
    const float scale = kidx ? 1.0f : ATTN_SCALE;
    const float fr = exp2f(-10.0f * (float)c16 * (1.0f / 15.0f));
#pragma unroll
    for (int mq = 0; mq < 4; mq++) {
#pragma unroll
      for (int rg = 0; rg < 4; rg++) {
        const int m = m0 + mo + mq * 16 + q4 * 4 + rg;
        const float x0 = acc[mq][0][rg], x1 = acc[mq][1][rg];
        const float x2 = acc[mq][2][rg], x3 = acc[mq][3][rg];
        float ss = x0 * x0 + x1 * x1 + x2 * x2 + x3 * x3;
        ss += __shfl_xor(ss, 1, 64);
        ss += __shfl_xor(ss, 2, 64);
        ss += __shfl_xor(ss, 4, 64);
        ss += __shfl_xor(ss, 8, 64);
        const float rinv = rsqrtf(ss * (1.0f / 64.0f) + RMS_EPS) * scale;
        const float xn0 = x0 * rinv, xn1 = x1 * rinv;
        const float xn2 = x2 * rinv, xn3 = x3 * rinv;
        float sn, cs;
        sincosf((float)m * fr, &sn, &cs);
        const float y0 = xn0 * cs + xn2 * sn;
        const float y2 = xn2 * cs - xn0 * sn;
        bf16* rp = dst + (size_t)(h * SEQ + m) * HD + c16;
        rp[0]  = (bf16)y0;
        rp[16] = (bf16)xn1;
        rp[32] = (bf16)y2;
        rp[48] = (bf16)xn3;
      }
    }
  }
}

__global__ __launch_bounds__(256) void gemm_proj(
    const bf16* __restrict__ A, const bf16* __restrict__ B, float* __restrict__ C)
{
  __shared__ bf16 As[128][40];
  __shared__ bf16 Bs[128][40];
  const int m0 = blockIdx.x * 128, n0 = blockIdx.y * 128;
  f32x4 acc[4][4];
  gemm128_core(A, B, m0, n0, As, Bs, acc);

  const int lane = threadIdx.x & 63, w = threadIdx.x >> 6;
  const int c16 = lane & 15, q4 = lane >> 4;
  const int mo = (w & 1) * 64, no = (w >> 1) * 64;
#pragma unroll
  for (int nq = 0; nq < 4; nq++) {
    const int n = n0 + no + nq * 16 + c16;
#pragma unroll
    for (int mq = 0; mq < 4; mq++) {
      const int mb = m0 + mo + mq * 16 + q4 * 4;
#pragma unroll
      for (int rg = 0; rg < 4; rg++)
        C[(size_t)(mb + rg) * DM + n] = acc[mq][nq][rg];
    }
  }
}

// ---------------------------------------------------------------------------
// Flash partial, BM=128, S^T orientation. Block = (qb 0..31, h, p).
// Per iter/wave: 8 b128 K-frag reads (hoisted, shared across f), S^T MFMA,
// exp/mask (lane-scalar l), b64 Pst writes, b128 ap reads, 8 b128 V reads.
// ---------------------------------------------------------------------------
__global__ __launch_bounds__(256) void flash_partial(
    const bf16* __restrict__ Qb, const bf16* __restrict__ Kb,
    const bf16* __restrict__ Vt, bf16* __restrict__ Opart,
    float* __restrict__ Lpart)
{
  __shared__ bf16 Ks[64][72];
  __shared__ bf16 Vts[64][72];
  __shared__ bf16 Pst[4][32][68];                 // [wave][q][s], stride 68: 8B-pair conflict-free
  const int h = blockIdx.y, p = blockIdx.z;
  const int qi = 31 - (int)blockIdx.x;            // LPT: heavy blocks first
  const int q0 = qi * 128;
  const int tid = threadIdx.x;
  const int lane = tid & 63, w = tid >> 6;
  const int c16 = lane & 15, q4 = lane >> 4;
  const int sr = tid >> 3, sc8 = (tid & 7) * 8;

  bf16x8 aq[2][2];
#pragma unroll
  for (int f = 0; f < 2; f++) {
    const int tq = q0 + w * 32 + f * 16 + c16;
    aq[f][0] = *(const bf16x8*)&Qb[((h * SEQ) + tq) * HD + q4 * 8];
    aq[f][1] = *(const bf16x8*)&Qb[((h * SEQ) + tq) * HD + 32 + q4 * 8];
  }
  const int qg[2] = { q0 + w * 32 + c16, q0 + w * 32 + 16 + c16 };  // this lane's q-row per f

  const f32x4 vzero = {0.f, 0.f, 0.f, 0.f};
  f32x4 O[2][4];
  float l_f[2] = {0.f, 0.f};
#pragma unroll
  for (int f = 0; f < 2; f++)
#pragma unroll
    for (int j = 0; j < 4; j++) O[f][j] = vzero;

  const bf16* Kbase = Kb + (size_t)h * SEQ * HD;
  const bf16* Vbase = Vt + (size_t)h * HD * SEQ;

  const int sEnd = q0 + 64;
  const int sBeg = p * 64;
  if (sBeg <= sEnd) {
    bf16x8 kr0 = *(const bf16x8*)&Kbase[(sBeg + sr) * HD + sc8];
    bf16x8 kr1 = *(const bf16x8*)&Kbase[(sBeg + sr + 32) * HD + sc8];
    bf16x8 vr0 = *(const bf16x8*)&Vbase[sr * SEQ + sBeg + sc8];
    bf16x8 vr1 = *(const bf16x8*)&Vbase[(sr + 32) * SEQ + sBeg + sc8];

    for (int s0 = sBeg; s0 <= sEnd; s0 += NPART * 64) {
      __syncthreads();
      *(bf16x8*)&Ks[sr][sc8]       = kr0;
      *(bf16x8*)&Ks[sr + 32][sc8]  = kr1;
      *(bf16x8*)&Vts[sr][sc8]      = vr0;
      *(bf16x8*)&Vts[sr + 32][sc8] = vr1;
      __syncthreads();

      const int snext = s0 + NPART * 64;
      if (snext <= sEnd) {
        kr0 = *(const bf16x8*)&Kbase[(snext + sr) * HD + sc8];
        kr1 = *(const bf16x8*)&Kbase[(snext + sr + 32) * HD + sc8];
        vr0 = *(const bf16x8*)&Vbase[sr * SEQ + snext + sc8];
        vr1 = *(const bf16x8*)&Vbase[(sr + 32) * SEQ + snext + sc8];
      }

      // K fragments: A-operand [m=s][k=d], read once, shared by both f
      bf16x8 kf0[4], kf1[4];
#pragma unroll
      for (int nt = 0; nt < 4; nt++) {
        kf0[nt] = *(const bf16x8*)&Ks[nt * 16 + c16][q4 * 8];
        kf1[nt] = *(const bf16x8*)&Ks[nt * 16 + c16][32 + q4 * 8];
      }
#pragma unroll
      for (int f = 0; f < 2; f++) {
        // S^T tile: D[m=s][n=q]; lane holds q=c16, s=nt*16+q4*4+rg
        f32x4 S[4];
#pragma unroll
        for (int nt = 0; nt < 4; nt++) {
          f32x4 z = vzero;
          z = MFMA_BF16(kf0[nt], aq[f][0], z);
          z = MFMA_BF16(kf1[nt], aq[f][1], z);
          S[nt] = z;
        }
        float lf = l_f[f];
#pragma unroll
        for (int nt = 0; nt < 4; nt++) {
#pragma unroll
          for (int rg = 0; rg < 4; rg++) {
            const int s_g = s0 + nt * 16 + q4 * 4 + rg;
            const float pv = (s_g > qg[f]) ? 0.f : __expf(S[nt][rg]);
            S[nt][rg] = pv;
            lf += pv;
          }
          bf16x4 pk = { (bf16)S[nt][0], (bf16)S[nt][1], (bf16)S[nt][2], (bf16)S[nt][3] };
          *(bf16x4*)&Pst[w][f * 16 + c16][nt * 16 + q4 * 4] = pk;
        }
        l_f[f] = lf;
      }
      // P fragments (A-op): contiguous b128 from Pst
      bf16x8 ap[2][2];
#pragma unroll
      for (int f = 0; f < 2; f++) {
        ap[f][0] = *(const bf16x8*)&Pst[w][f * 16 + c16][q4 * 8];
        ap[f][1] = *(const bf16x8*)&Pst[w][f * 16 + c16][32 + q4 * 8];
      }
#pragma unroll
      for (int dt = 0; dt < 4; dt++) {
        bf16x8 bv0 = *(const bf16x8*)&Vts[dt * 16 + c16][q4 * 8];
        bf16x8 bv1 = *(const bf16x8*)&Vts[dt * 16 + c16][32 + q4 * 8];
#pragma unroll
        for (int f = 0; f < 2; f++) {
          O[f][dt] = MFMA_BF16(ap[f][0], bv0, O[f][dt]);
          O[f][dt] = MFMA_BF16(ap[f][1], bv1, O[f][dt]);
        }
      }
    }
  }
  // l: lane holds full sum for q-row c16 (per f) over its (q4, nt, rg) share
#pragma unroll
  for (int f = 0; f < 2; f++) {
    float l = l_f[f];
    l += __shfl_xor(l, 16, 64);
    l += __shfl_xor(l, 32, 64);
    l_f[f] = l;
  }
  const int u = ((h * 32 + qi) * NPART + p);
  bf16* Op = Opart + (size_t)u * 8192;            // 128 x 64
#pragma unroll
  for (int f = 0; f < 2; f++)
#pragma unroll
    for (int dt = 0; dt < 4; dt++)
#pragma unroll
      for (int rg = 0; rg < 4; rg++)
        Op[(w * 32 + f * 16 + q4 * 4 + rg) * 64 + dt * 16 + c16] = (bf16)O[f][dt][rg];
  if (lane < 32) {                                // q4 == 0 or 1 -> one writer per row
    if (q4 == 0) {
#pragma unroll
      for (int f = 0; f < 2; f++)
        Lpart[u * 128 + w * 32 + f * 16 + c16] = l_f[f];
    }
  }
}

// ---------------------------------------------------------------------------
// Combine: Y = (sum_p O_p) / (sum_p l_p). Block per 64-row chunk x head.
// ---------------------------------------------------------------------------
__global__ __launch_bounds__(256) void flash_combine(
    const bf16* __restrict__ Opart, const float* __restrict__ Lpart,
    bf16* __restrict__ Y)
{
  const int q64 = blockIdx.x, h = blockIdx.y;
  const int qi = q64 >> 1, roff = (q64 & 1) * 64;
  const int row = threadIdx.x >> 2, cg = (threadIdx.x & 3) * 16;
  const int u0 = (h * 32 + qi) * NPART;
  const int r128 = roff + row;
  float lsum = 0.f;
#pragma unroll
  for (int p = 0; p < NPART; p++) lsum += Lpart[(u0 + p) * 128 + r128];
  const float inv = 1.0f / lsum;
  const bf16* O0 = Opart + (size_t)u0 * 8192 + r128 * 64 + cg;
  bf16* yp = Y + (size_t)(q64 * 64 + row) * DM + h * HD + cg;
#pragma unroll
  for (int j = 0; j < 16; j += 8) {
    float s[8] = {0, 0, 0, 0, 0, 0, 0, 0};
#pragma unroll
    for (int p = 0; p < NPART; p++) {
      bf16x8 a = *(const bf16x8*)(O0 + p * 8192 + j);
#pragma unroll
      for (int e = 0; e < 8; e++) s[e] += (float)a[e];
    }
#pragma unroll
    for (int e = 0; e < 8; e++) yp[j + e] = (bf16)(s[e] * inv);
  }
}

// ---------------------------------------------------------------------------
extern "C" void kernel_launch(void* const* d_in, const int* in_sizes, int n_in,
                              void* d_out, int out_size, void* d_ws, size_t ws_size,
                              hipStream_t stream)
{
  (void)in_sizes; (void)n_in; (void)out_size; (void)ws_size;
  const float* x      = (const float*)d_in[0];
  const float* qkvw   = (const float*)d_in[1];
  const float* cprojw = (const float*)d_in[2];
  float* outp = (float*)d_out;

  const int NX = SEQ * DM, NW = NQKV * DM, NP = DM * DM;

  char* ws = (char*)d_ws;
  bf16*  xb    = (bf16*)(ws);                       // 6,291,456
  bf16*  wqkv  = (bf16*)(ws + 6291456);             // 3,538,944
  bf16*  wproj = (bf16*)(ws + 9830400);             // 1,179,648
  bf16*  Q     = (bf16*)(ws + 11010048);            // 6,291,456
  bf16*  K     = (bf16*)(ws + 17301504);            // 6,291,456
  bf16*  Vt    = (bf16*)(ws + 23592960);            // 6,291,456
  bf16*  Y     = (bf16*)(ws + 29884416);            // 6,291,456
  bf16*  Opart = (bf16*)(ws + 36175872);            // 25,165,824 (1536 x 8192 bf16)
  float* Lpart = (float*)(ws + 61341696);           //    786,432  (total 62.1 MB)

  convert_in<<<dim3(NX / 2048), 256, 0, stream>>>(x,      xb,    NX);
  convert_in<<<dim3(NW / 2048), 256, 0, stream>>>(qkvw,   wqkv,  NW);
  convert_in<<<dim3(NP / 2048), 256, 0, stream>>>(cprojw, wproj, NP);

  gemm_qkv     <<<dim3(SEQ / 128, NQKV / 128), 256, 0, stream>>>(xb, wqkv, Q, K, Vt);
  flash_partial<<<dim3(SEQ / 128, NH, NPART),  256, 0, stream>>>(Q, K, Vt, Opart, Lpart);
  flash_combine<<<dim3(SEQ / 64, NH),          256, 0, stream>>>(Opart, Lpart, Y);
  gemm_proj    <<<dim3(SEQ / 128, DM / 128),   256, 0, stream>>>(Y, wproj, outp);
}